// Round 18
// baseline (159.278 us; speedup 1.0000x reference)
//
#include <hip/hip_runtime.h>
#include <math.h>

#define NPG 128      // nodes per graph
#define HID 64
#define ICH 151
#define EPG 2048     // edges per graph
#define TPB 512      // 8 waves
#define EPT (EPG / TPB)
#define KP  160      // W1T padded K (5 MFMA k-steps of 32)
#define HTS 136      // h^T row stride, bf16 (272B: 16B-aligned, 2-way banks)
#define ASS 132      // As row stride, f32 (528B: 16B-aligned, 2-way banks)
#define AS_OFF 17408 // byte offset of As region (= ht bytes)
#define GRID 768     // 3 persistent blocks per CU (256 CUs)

typedef __attribute__((ext_vector_type(8))) short  short8;   // bf16x8 frag
typedef __attribute__((ext_vector_type(4))) float  floatx4;  // f32x4 acc

// software fp32->bf16 RNE (proven R4/R6/R8/R10-R17; cvt_pk asm NaN'd R7/R9)
static __device__ __forceinline__ unsigned short f2bf(float v) {
    unsigned u = __builtin_bit_cast(unsigned, v);
    return (unsigned short)((u + 0x7fffu + ((u >> 16) & 1u)) >> 16);
}
static __device__ __forceinline__ unsigned packbf(float a, float b) {
    return (unsigned)f2bf(a) | ((unsigned)f2bf(b) << 16);
}
static __device__ __forceinline__ short8 pack8(const float* v) {
    union { unsigned u[4]; short8 s; } r;
    r.u[0] = packbf(v[0], v[1]);
    r.u[1] = packbf(v[2], v[3]);
    r.u[2] = packbf(v[4], v[5]);
    r.u[3] = packbf(v[6], v[7]);
    return r.s;
}

// ---- prep: W1 [151][64] f32 -> W1T [64][160] bf16 (k-pad zeroed) ----
__global__ __launch_bounds__(512) void gcn_prep(const float* __restrict__ W1,
                                                short* __restrict__ W1T) {
    int i = threadIdx.x + blockIdx.x * 512;          // 10240 elements exactly
    if (i < HID * KP) {
        int ch = i / KP, k = i - ch * KP;
        W1T[i] = (short)f2bf((k < ICH) ? W1[k * HID + ch] : 0.0f);
    }
}

__global__ __launch_bounds__(TPB, 6) void gcn_fused(
    const float* __restrict__ x,       // [N,151]
    const int*   __restrict__ erow,    // [E]
    const int*   __restrict__ ecol,    // [E]
    const float* __restrict__ ew,      // [E]
    const short* __restrict__ W1T,     // [64][160] bf16 (prepped)
    const float* __restrict__ b1,      // [64]
    const float* __restrict__ Wlin,    // [8192]
    const float* __restrict__ blin,    // [1]
    float* __restrict__ out,           // [B]
    int B)
{
    // LDS 51200 B + ~0.6KB statics -> 3 blocks/CU (persistent):
    //   ht = smem[0 .. 17408)        64x136 bf16 h^T (GEMM out, agg B-frags)
    //   As = smem[17408 .. 51200)    64x132 f32 RAW half-adjacency
    __shared__ __align__(16) char smem[AS_OFF + 64 * ASS * 4];
    __shared__ float deg[NPG];
    __shared__ float red[TPB / 64];

    short* ht = (short*)smem;
    float* As = (float*)(smem + AS_OFF);

    const int t    = threadIdx.x;
    const int lane = t & 63;
    const int wv   = t >> 6;
    const int c16  = lane & 15;
    const int kq   = (lane >> 4) * 8;

    const int mrow  = (wv >> 1) * 16 + c16;            // dst row within half
    const int rbase = (wv >> 1) * 16 + (lane >> 4) * 4;

    // ============ persistent loop: 2-3 graphs per block ============
    for (int g = blockIdx.x; g < B; g += GRID) {

        // ---- per-iter preamble: deg init + zero As(half0) ----
        if (t < NPG) deg[t] = 1.0f;                    // self-loop weight
        for (int p = t; p < 64 * ASS / 4; p += TPB)
            ((floatx4*)As)[p] = (floatx4){0.0f, 0.0f, 0.0f, 0.0f};
        __syncthreads();                               // bar0

        // ================= I1: the fat interval =================
        int   ep_[EPT];                                // (cl<<7) | rl
        float nw_[EPT];                                // raw w
        const int ebase = g * EPG;
        #pragma unroll
        for (int it = 0; it < EPT; ++it) {
            int e = ebase + t + it * TPB;
            int rl = erow[e] & (NPG - 1);
            int cl = ecol[e] & (NPG - 1);
            ep_[it] = (cl << 7) | rl;
            nw_[it] = ew[e];
        }

        short8 af[5];                                  // x A-frags (direct loads)
        {
            const float* xr = x + (size_t)g * (NPG * ICH) + (wv * 16 + c16) * ICH;
            #pragma unroll
            for (int s = 0; s < 5; ++s) {
                float v[8];
                #pragma unroll
                for (int j = 0; j < 8; ++j) {
                    int k = s * 32 + kq + j;
                    v[j] = (k < ICH) ? xr[k] : 0.0f;
                }
                af[s] = pack8(v);
            }
        }

        // deg atomics + RAW scatter half0 + diag0 (no deg dependency)
        #pragma unroll
        for (int it = 0; it < EPT; ++it) {
            int rl = ep_[it] & (NPG - 1), cl = ep_[it] >> 7;
            atomicAdd(&deg[cl], nw_[it]);
            if ((cl >> 6) == 0)
                atomicAdd(&As[(cl & 63) * ASS + rl], nw_[it]);
        }
        if (t < 64)
            atomicAdd(&As[t * ASS + t], 1.0f);         // raw self-loop

        // GEMM h = x @ W1 -> ht (global W1T B-frags) hides the atomics
        #pragma unroll
        for (int n = 0; n < 4; ++n) {
            floatx4 acc = {0.0f, 0.0f, 0.0f, 0.0f};
            #pragma unroll
            for (int s = 0; s < 5; ++s) {
                short8 b = *(const short8*)&W1T[(n * 16 + c16) * KP + s * 32 + kq];
                acc = __builtin_amdgcn_mfma_f32_16x16x32_bf16(af[s], b, acc, 0, 0, 0);
            }
            int col = n * 16 + c16;
            int row = wv * 16 + (lane >> 4) * 4;
            *(int2*)&ht[col * HTS + row] =
                make_int2((int)packbf(acc[0], acc[1]), (int)packbf(acc[2], acc[3]));
        }
        __syncthreads();                               // bar1: deg/As0/ht final

        // ================= I2: half0 frags + MFMA + relu =================
        float v0[2][4];
        {
            short8 afr[4];
            #pragma unroll
            for (int ks = 0; ks < 4; ++ks) {           // col-scale by dinv[src]
                const float* ap = &As[mrow * ASS + ks * 32 + kq];
                floatx4 a0 = *(const floatx4*)ap;
                floatx4 a1 = *(const floatx4*)(ap + 4);
                floatx4 d0 = *(const floatx4*)&deg[ks * 32 + kq];
                floatx4 d1 = *(const floatx4*)&deg[ks * 32 + kq + 4];
                float v[8];
                #pragma unroll
                for (int j = 0; j < 4; ++j) {
                    v[j]     = a0[j] * rsqrtf(d0[j]);
                    v[4 + j] = a1[j] * rsqrtf(d1[j]);
                }
                afr[ks] = pack8(v);
            }
            float rs[4];
            #pragma unroll
            for (int r = 0; r < 4; ++r)                // row-scale dinv[dst]
                rs[r] = rsqrtf(deg[rbase + r]);
            #pragma unroll
            for (int nn = 0; nn < 2; ++nn) {
                int col = ((wv & 1) * 2 + nn) * 16 + c16;
                floatx4 acc = {0.0f, 0.0f, 0.0f, 0.0f};
                #pragma unroll
                for (int ks = 0; ks < 4; ++ks) {
                    short8 b = *(const short8*)&ht[col * HTS + ks * 32 + kq];
                    acc = __builtin_amdgcn_mfma_f32_16x16x32_bf16(afr[ks], b, acc, 0, 0, 0);
                }
                float b1v = b1[col];
                #pragma unroll
                for (int r = 0; r < 4; ++r)
                    v0[nn][r] = fmaxf(acc[r] * rs[r] + b1v, 0.0f);
            }
        }
        __syncthreads();                               // bar2: As0 reads done

        // ============ I3: zero As(half1) + deferred Wlin0 dot ============
        for (int p = t; p < 64 * ASS / 4; p += TPB)
            ((floatx4*)As)[p] = (floatx4){0.0f, 0.0f, 0.0f, 0.0f};
        float partial = 0.0f;
        #pragma unroll
        for (int nn = 0; nn < 2; ++nn) {
            int col = ((wv & 1) * 2 + nn) * 16 + c16;
            #pragma unroll
            for (int r = 0; r < 4; ++r)
                partial += v0[nn][r] * Wlin[(rbase + r) * HID + col];
        }
        __syncthreads();                               // bar3: zero1 done

        // ================= I4: scatter half1 =================
        #pragma unroll
        for (int it = 0; it < EPT; ++it) {
            int cl = ep_[it] >> 7;
            if ((cl >> 6) == 1)
                atomicAdd(&As[(cl & 63) * ASS + (ep_[it] & (NPG - 1))], nw_[it]);
        }
        if (t < 64)
            atomicAdd(&As[t * ASS + 64 + t], 1.0f);    // raw self-loop
        __syncthreads();                               // bar4: As1 built

        // ========= I5: half1 frags + MFMA + epilogue + reduce =========
        {
            short8 afr[4];
            #pragma unroll
            for (int ks = 0; ks < 4; ++ks) {
                const float* ap = &As[mrow * ASS + ks * 32 + kq];
                floatx4 a0 = *(const floatx4*)ap;
                floatx4 a1 = *(const floatx4*)(ap + 4);
                floatx4 d0 = *(const floatx4*)&deg[ks * 32 + kq];
                floatx4 d1 = *(const floatx4*)&deg[ks * 32 + kq + 4];
                float v[8];
                #pragma unroll
                for (int j = 0; j < 4; ++j) {
                    v[j]     = a0[j] * rsqrtf(d0[j]);
                    v[4 + j] = a1[j] * rsqrtf(d1[j]);
                }
                afr[ks] = pack8(v);
            }
            float rs[4];
            #pragma unroll
            for (int r = 0; r < 4; ++r)
                rs[r] = rsqrtf(deg[64 + rbase + r]);
            #pragma unroll
            for (int nn = 0; nn < 2; ++nn) {
                int col = ((wv & 1) * 2 + nn) * 16 + c16;
                floatx4 acc = {0.0f, 0.0f, 0.0f, 0.0f};
                #pragma unroll
                for (int ks = 0; ks < 4; ++ks) {
                    short8 b = *(const short8*)&ht[col * HTS + ks * 32 + kq];
                    acc = __builtin_amdgcn_mfma_f32_16x16x32_bf16(afr[ks], b, acc, 0, 0, 0);
                }
                float b1v = b1[col];
                #pragma unroll
                for (int r = 0; r < 4; ++r) {
                    float v = fmaxf(acc[r] * rs[r] + b1v, 0.0f);
                    partial += v * Wlin[(64 + rbase + r) * HID + col];
                }
            }
        }

        // ---- block reduction + sigmoid ----
        #pragma unroll
        for (int o = 32; o > 0; o >>= 1)
            partial += __shfl_down(partial, o, 64);
        if (lane == 0) red[wv] = partial;
        __syncthreads();                               // bar5
        if (t == 0) {
            float tot = blin[0];
            #pragma unroll
            for (int i = 0; i < TPB / 64; ++i) tot += red[i];
            out[g] = 1.0f / (1.0f + expf(-tot));
        }
        // next iteration's bar0 protects red/deg/As reuse
    }
}

extern "C" void kernel_launch(void* const* d_in, const int* in_sizes, int n_in,
                              void* d_out, int out_size, void* d_ws, size_t ws_size,
                              hipStream_t stream) {
    const float* x    = (const float*)d_in[0];
    const int*   ei   = (const int*)d_in[1];
    const float* ew   = (const float*)d_in[2];
    const float* W1   = (const float*)d_in[4];
    const float* b1   = (const float*)d_in[5];
    const float* Wlin = (const float*)d_in[6];
    const float* blin = (const float*)d_in[7];
    float* out = (float*)d_out;

    const int E = in_sizes[1] / 2;     // edge_index is [2, E]
    const int B = out_size;            // 2048 graphs

    short* W1T = (short*)d_ws;         // [64][160] bf16 = 20480 B

    gcn_prep<<<(HID * KP + 511) / 512, 512, 0, stream>>>(W1, W1T);
    gcn_fused<<<GRID, TPB, 0, stream>>>(x, ei, ei + E, ew, W1T, b1, Wlin, blin,
                                        out, B);
}

// Round 19
// 83.884 us; speedup vs baseline: 1.8988x; 1.8988x over previous
//
#include <hip/hip_runtime.h>
#include <math.h>

#define NPG 128      // nodes per graph
#define HID 64
#define ICH 151
#define EPG 2048     // edges per graph
#define TPB 512      // 8 waves
#define EPT (EPG / TPB)
#define KP  160      // W1T padded K (5 MFMA k-steps of 32)
#define HTS 136      // h^T row stride, bf16 (272B: 16B-aligned, 2-way banks)
#define ABS 136      // Ab row stride, bf16 (272B: 16B-aligned, 2-way banks)
#define AB_OFF 17408 // byte offset of Ab region (= ht bytes)

typedef __attribute__((ext_vector_type(8))) short  short8;   // bf16x8 frag
typedef __attribute__((ext_vector_type(4))) float  floatx4;  // f32x4 acc

// software fp32->bf16 RNE (proven R4/R6/R8/R10-R18; cvt_pk asm NaN'd R7/R9)
static __device__ __forceinline__ unsigned short f2bf(float v) {
    unsigned u = __builtin_bit_cast(unsigned, v);
    return (unsigned short)((u + 0x7fffu + ((u >> 16) & 1u)) >> 16);
}
static __device__ __forceinline__ float bf2f(short b) {
    return __builtin_bit_cast(float, ((unsigned)(unsigned short)b) << 16);
}
static __device__ __forceinline__ unsigned packbf(float a, float b) {
    return (unsigned)f2bf(a) | ((unsigned)f2bf(b) << 16);
}
static __device__ __forceinline__ short8 pack8(const float* v) {
    union { unsigned u[4]; short8 s; } r;
    r.u[0] = packbf(v[0], v[1]);
    r.u[1] = packbf(v[2], v[3]);
    r.u[2] = packbf(v[4], v[5]);
    r.u[3] = packbf(v[6], v[7]);
    return r.s;
}

// bf16 += w at linear index idx of a bf16 LDS array (dword CAS; handles dups)
static __device__ __forceinline__ void lds_bf16_add(short* base, int idx, float w) {
    unsigned* a = (unsigned*)base + (idx >> 1);
    unsigned sh = (unsigned)(idx & 1) << 4;
    unsigned cur = *(volatile unsigned*)a;
    for (;;) {
        unsigned old = cur;
        float f = __builtin_bit_cast(float, ((old >> sh) & 0xFFFFu) << 16) + w;
        unsigned nw2 = (old & ~(0xFFFFu << sh)) | ((unsigned)f2bf(f) << sh);
        cur = atomicCAS(a, old, nw2);
        if (cur == old) break;
    }
}

// ---- prep: W1 [151][64] f32 -> W1T [64][160] bf16 (k-pad zeroed) ----
__global__ __launch_bounds__(512) void gcn_prep(const float* __restrict__ W1,
                                                short* __restrict__ W1T) {
    int i = threadIdx.x + blockIdx.x * 512;          // 10240 elements exactly
    if (i < HID * KP) {
        int ch = i / KP, k = i - ch * KP;
        W1T[i] = (short)f2bf((k < ICH) ? W1[k * HID + ch] : 0.0f);
    }
}

__global__ __launch_bounds__(TPB, 6) void gcn_fused(
    const float* __restrict__ x,       // [N,151]
    const int*   __restrict__ erow,    // [E]
    const int*   __restrict__ ecol,    // [E]
    const float* __restrict__ ew,      // [E]
    const short* __restrict__ W1T,     // [64][160] bf16 (prepped)
    const float* __restrict__ b1,      // [64]
    const float* __restrict__ Wlin,    // [8192]
    const float* __restrict__ blin,    // [1]
    float* __restrict__ out)           // [B]
{
    // LDS 52224 B + ~0.6KB statics -> 3 blocks/CU:
    //   ht = smem[0 .. 17408)        64x136 bf16 h^T (GEMM out, agg B-frags)
    //   Ab = smem[17408 .. 52224)    128x136 bf16 FULL raw adjacency
    __shared__ __align__(16) char smem[AB_OFF + NPG * ABS * 2];
    __shared__ float deg[NPG];
    __shared__ float red[TPB / 64];

    short* ht = (short*)smem;
    short* Ab = (short*)(smem + AB_OFF);

    const int t    = threadIdx.x;
    const int g    = blockIdx.x;
    const int lane = t & 63;
    const int wv   = t >> 6;
    const int c16  = lane & 15;
    const int kq   = (lane >> 4) * 8;

    // ---- preamble: deg init + zero Ab with fused diagonal (bf16 1.0) ----
    if (t < NPG) deg[t] = 1.0f;                       // self-loop weight
    {
        // 34816 B = 2176 x 16B chunks; chunk p covers bf16 idx [8p, 8p+8).
        // Diagonal element i sits at linear idx i*137 -> at most one per chunk.
        for (int p = t; p < NPG * ABS / 8; p += TPB) {
            union { int4 i4; short s[8]; } c;
            c.i4 = make_int4(0, 0, 0, 0);
            int i = (8 * p + 136) / 137;               // candidate diag row
            int d = i * 137 - 8 * p;
            if (i < NPG && d >= 0 && d < 8)
                c.s[d] = (short)0x3F80;                // bf16 1.0
            *(int4*)&Ab[p * 8] = c.i4;
        }
    }
    __syncthreads();                                   // bar0

    // ================= I1: the single fat interval =================
    // edges -> regs (one coalesced scan)
    int   ep_[EPT];                                    // (cl<<7) | rl
    float nw_[EPT];                                    // raw w
    const int ebase = g * EPG;
    #pragma unroll
    for (int it = 0; it < EPT; ++it) {
        int e = ebase + t + it * TPB;
        int rl = erow[e] & (NPG - 1);
        int cl = ecol[e] & (NPG - 1);
        ep_[it] = (cl << 7) | rl;
        nw_[it] = ew[e];
    }

    // x A-fragments: direct guarded scalar loads (proven best)
    short8 af[5];
    {
        const float* xr = x + (size_t)g * (NPG * ICH) + (wv * 16 + c16) * ICH;
        #pragma unroll
        for (int s = 0; s < 5; ++s) {
            float v[8];
            #pragma unroll
            for (int j = 0; j < 8; ++j) {
                int k = s * 32 + kq + j;
                v[j] = (k < ICH) ? xr[k] : 0.0f;
            }
            af[s] = pack8(v);
        }
    }

    // deg atomics + FULL raw A scatter (bf16 CAS add; handles duplicates)
    #pragma unroll
    for (int it = 0; it < EPT; ++it) {
        int rl = ep_[it] & (NPG - 1), cl = ep_[it] >> 7;
        atomicAdd(&deg[cl], nw_[it]);
        lds_bf16_add(Ab, cl * ABS + rl, nw_[it]);
    }

    // GEMM h = x @ W1 -> ht (global W1T B-frags) hides the atomics above
    #pragma unroll
    for (int n = 0; n < 4; ++n) {
        floatx4 acc = {0.0f, 0.0f, 0.0f, 0.0f};
        #pragma unroll
        for (int s = 0; s < 5; ++s) {
            short8 b = *(const short8*)&W1T[(n * 16 + c16) * KP + s * 32 + kq];
            acc = __builtin_amdgcn_mfma_f32_16x16x32_bf16(af[s], b, acc, 0, 0, 0);
        }
        // D: row = (lane>>4)*4 + r, col = n*16 + c16  -> ht[col][row]
        int col = n * 16 + c16;
        int row = wv * 16 + (lane >> 4) * 4;
        *(int2*)&ht[col * HTS + row] =
            make_int2((int)packbf(acc[0], acc[1]), (int)packbf(acc[2], acc[3]));
    }
    __syncthreads();                                   // bar1: deg/Ab/ht final

    // ========== I2: single agg pass, K=128, all 128 dst rows ==========
    const int arow  = wv * 16 + c16;                   // this wave's dst rows
    const int rbase = wv * 16 + (lane >> 4) * 4;       // D rows (dst nodes)

    short8 afr[4];                                     // A-frags, dinv[src]-scaled
    #pragma unroll
    for (int ks = 0; ks < 4; ++ks) {
        short8 a = *(const short8*)&Ab[arow * ABS + ks * 32 + kq];
        float v[8];
        #pragma unroll
        for (int j = 0; j < 8; ++j)
            v[j] = bf2f(a[j]) * rsqrtf(deg[ks * 32 + kq + j]);
        afr[ks] = pack8(v);
    }
    float rs[4];
    #pragma unroll
    for (int r = 0; r < 4; ++r)                        // dinv[dst] row scale
        rs[r] = rsqrtf(deg[rbase + r]);

    float partial = 0.0f;
    #pragma unroll
    for (int nt = 0; nt < 4; ++nt) {
        int col = nt * 16 + c16;
        floatx4 acc = {0.0f, 0.0f, 0.0f, 0.0f};
        #pragma unroll
        for (int ks = 0; ks < 4; ++ks) {
            short8 b = *(const short8*)&ht[col * HTS + ks * 32 + kq];
            acc = __builtin_amdgcn_mfma_f32_16x16x32_bf16(afr[ks], b, acc, 0, 0, 0);
        }
        float b1v = b1[col];
        #pragma unroll
        for (int r = 0; r < 4; ++r) {
            float v = fmaxf(acc[r] * rs[r] + b1v, 0.0f);
            partial += v * Wlin[(rbase + r) * HID + col];
        }
    }

    // ---- block reduction + sigmoid ----
    #pragma unroll
    for (int o = 32; o > 0; o >>= 1)
        partial += __shfl_down(partial, o, 64);
    if (lane == 0) red[wv] = partial;
    __syncthreads();                                   // bar2
    if (t == 0) {
        float tot = blin[0];
        #pragma unroll
        for (int i = 0; i < TPB / 64; ++i) tot += red[i];
        out[g] = 1.0f / (1.0f + expf(-tot));
    }
}

extern "C" void kernel_launch(void* const* d_in, const int* in_sizes, int n_in,
                              void* d_out, int out_size, void* d_ws, size_t ws_size,
                              hipStream_t stream) {
    const float* x    = (const float*)d_in[0];
    const int*   ei   = (const int*)d_in[1];
    const float* ew   = (const float*)d_in[2];
    const float* W1   = (const float*)d_in[4];
    const float* b1   = (const float*)d_in[5];
    const float* Wlin = (const float*)d_in[6];
    const float* blin = (const float*)d_in[7];
    float* out = (float*)d_out;

    const int E = in_sizes[1] / 2;     // edge_index is [2, E]
    const int B = out_size;            // 2048 graphs

    short* W1T = (short*)d_ws;         // [64][160] bf16 = 20480 B

    gcn_prep<<<(HID * KP + 511) / 512, 512, 0, stream>>>(W1, W1T);
    gcn_fused<<<B, TPB, 0, stream>>>(x, ei, ei + E, ew, W1T, b1, Wlin, blin, out);
}